// Round 12
// baseline (281.109 us; speedup 1.0000x reference)
//
#include <hip/hip_runtime.h>
#include <hip/hip_bf16.h>
#include <stdint.h>

// Problem constants (FlaxGPTNeoSelfAttention): B=2, S=2048, D=2048, H=16, HD=128
#define Bv 2
#define Sv 2048
#define Dv 2048
#define Hv 16
#define HDv 128
#define Mv (Bv*Sv)   // 4096 rows for the projection GEMMs

typedef __attribute__((ext_vector_type(8))) short short8;
typedef __attribute__((ext_vector_type(4))) short short4v;
typedef __attribute__((ext_vector_type(4))) float f32x4;
typedef __attribute__((ext_vector_type(16))) float f32x16;

union PU { uint32_t u[4]; short8 s; };

__device__ __forceinline__ unsigned short bf16_rne(float f) {
    union { float f; uint32_t u; } c; c.f = f;
    uint32_t u = c.u;
    u += 0x7fffu + ((u >> 16) & 1u);   // round-to-nearest-even
    return (unsigned short)(u >> 16);
}

__device__ __forceinline__ uint32_t cvt_pk_bf16(float lo, float hi) {
    uint32_t r;
    asm("v_cvt_pk_bf16_f32 %0, %1, %2" : "=v"(r) : "v"(lo), "v"(hi));
    return r;
}

__device__ __forceinline__ void gload16(const void* g, void* l) {
    // async global->LDS, 16B per lane; LDS dest = wave-uniform base + lane*16
    __builtin_amdgcn_global_load_lds((const __attribute__((address_space(1))) void*)g,
                                     (__attribute__((address_space(3))) void*)l, 16, 0, 0);
}

#define BARRIER() asm volatile("s_barrier" ::: "memory")
#define LGKM0()   do { asm volatile("s_waitcnt lgkmcnt(0)" ::: "memory"); \
                       __builtin_amdgcn_sched_barrier(0); } while (0)

// ---------------- kernel 1: hidden_states fp32 -> bf16 ----------------
__global__ void cvt_x_kernel(const float* __restrict__ x, unsigned short* __restrict__ xb) {
    int i = (blockIdx.x * 256 + threadIdx.x) * 4;
    float4 v = *(const float4*)(x + i);
    short4v o;
    o[0] = (short)bf16_rne(v.x);
    o[1] = (short)bf16_rne(v.y);
    o[2] = (short)bf16_rne(v.z);
    o[3] = (short)bf16_rne(v.w);
    *(short4v*)(xb + i) = o;
}

// ---------------- kernel 2: weights fp32 -> bf16, transposed Wt[n][k] ----------------
__global__ void cvt_wt_kernel(const float* __restrict__ w0, const float* __restrict__ w1,
                              const float* __restrict__ w2, const float* __restrict__ w3,
                              unsigned short* __restrict__ wt) {
    __shared__ unsigned short t[64][65];
    int z = blockIdx.z;
    const float* w = (z == 0) ? w0 : (z == 1) ? w1 : (z == 2) ? w2 : w3;
    unsigned short* o = wt + (size_t)z * Dv * Dv;
    int k0 = blockIdx.x * 64, n0 = blockIdx.y * 64;
    for (int i = threadIdx.x; i < 4096; i += 256) {
        int r = i >> 6, c = i & 63;
        t[r][c] = bf16_rne(w[(size_t)(k0 + r) * Dv + n0 + c]);
    }
    __syncthreads();
    for (int i = threadIdx.x; i < 4096; i += 256) {
        int r = i >> 6, c = i & 63;
        o[(size_t)(n0 + r) * Dv + k0 + c] = t[c][r];
    }
}

// ---------------- kernel 2b: V (bf16 [4096][2048]) -> VT per batch ([b*2048+c][s]) ----------------
__global__ void vt_kernel(const unsigned short* __restrict__ V, unsigned short* __restrict__ VT) {
    __shared__ unsigned short t[64 * 64];   // XOR chunk-swizzled 64x64 tile
    const int tid = threadIdx.x;
    const int b = blockIdx.z;
    const int s0 = blockIdx.x * 64, c0 = blockIdx.y * 64;
    const unsigned short* Vb = V + (size_t)b * Sv * Dv;
    unsigned short* VTb = VT + (size_t)b * Dv * Sv;
    #pragma unroll
    for (int ii = 0; ii < 2; ++ii) {
        int i = tid + ii * 256;
        int r = i >> 3, ch = i & 7;
        short8 v = *(const short8*)&Vb[(size_t)(s0 + r) * Dv + c0 + ch * 8];
        *(short8*)&t[r * 64 + ((ch ^ (r & 7)) << 3)] = v;
    }
    __syncthreads();
    #pragma unroll
    for (int ii = 0; ii < 2; ++ii) {
        int o = tid + ii * 256;
        int orow = o >> 3, och = o & 7;
        short8 v;
        #pragma unroll
        for (int j = 0; j < 8; ++j) {
            int r = och * 8 + j;
            int c = orow;
            v[j] = (short)t[r * 64 + ((((c >> 3) ^ (r & 7)) << 3) | (c & 7))];
        }
        *(short8*)&VTb[(size_t)(c0 + orow) * Sv + s0 + och * 8] = v;
    }
}

// ---------------- kernel 3a: QK projection, 8-phase 256x256 ----------------
__global__ __launch_bounds__(512, 2) void gemm8ph_kernel(
    const unsigned short* __restrict__ A,
    const unsigned short* __restrict__ WtBase,
    unsigned short* __restrict__ CbBase)
{
    extern __shared__ unsigned short lds[];   // 65536 shorts = 128 KiB
    const int tid = threadIdx.x;
    const int wv = tid >> 6, ln = tid & 63;
    const int lr = ln & 15, lg = ln >> 4;
    const int wm = wv >> 2, wn = wv & 3;      // 2 x 4 waves

    const int bid = blockIdx.x;
    const int xcd = bid & 7, idx = bid >> 3;
    const int n_idx = xcd * 2 + idx / 16;     // 0..15
    const int m_idx = idx % 16;
    const int m0 = m_idx * 256, n0g = n_idx * 256;

    const int lrow = wv * 8 + (ln >> 3);
    const int lcol = ((ln & 7) ^ (ln >> 3)) << 3;
    const unsigned short* Ag = A      + (size_t)(m0  + lrow) * Dv + lcol;
    const unsigned short* Bg = WtBase + (size_t)(n0g + lrow) * Dv + lcol;

    auto SH = [&](int T, int isB, int h) {
        const unsigned short* src = (isB ? Bg : Ag) + (size_t)(h * 128) * Dv + T * 64;
        unsigned short* dst = &lds[(T & 1) * 32768 + isB * 16384 + h * 8192 + wv * 512];
        gload16(src, dst);
        gload16(src + (size_t)64 * Dv, dst + 4096);
    };

    const int axk = lr & 7;
    auto RDA = [&](int buf, int fm, int ks) {
        return *(const short8*)&lds[buf * 32768 + (wm * 128 + fm * 16 + lr) * 64 + (((ks * 4 + lg) ^ axk) << 3)];
    };
    auto RDB = [&](int buf, int fn, int ks) {
        return *(const short8*)&lds[buf * 32768 + 16384 + (wn * 64 + fn * 16 + lr) * 64 + (((ks * 4 + lg) ^ axk) << 3)];
    };

    f32x4 acc[8][4];
    #pragma unroll
    for (int fm = 0; fm < 8; fm++)
        #pragma unroll
        for (int fn = 0; fn < 4; fn++)
            acc[fm][fn] = (f32x4){0.f, 0.f, 0.f, 0.f};

    SH(0, 0, 0); SH(0, 0, 1); SH(0, 1, 0); SH(0, 1, 1);
    SH(1, 1, 0); SH(1, 0, 0);
    asm volatile("s_waitcnt vmcnt(4)" ::: "memory");
    BARRIER();

    short8 af[8], b0[4], b1[4];
    const int NT2 = 16;

    #define MFMA_BLK(FN0, FN1, BARR) do {                                              \
        __builtin_amdgcn_s_setprio(1);                                                 \
        _Pragma("unroll")                                                              \
        for (int fm = 0; fm < 8; fm++) {                                               \
            acc[fm][FN0] = __builtin_amdgcn_mfma_f32_16x16x32_bf16(af[fm], BARR[FN0], acc[fm][FN0], 0, 0, 0); \
            acc[fm][FN1] = __builtin_amdgcn_mfma_f32_16x16x32_bf16(af[fm], BARR[FN1], acc[fm][FN1], 0, 0, 0); \
        }                                                                              \
        __builtin_amdgcn_s_setprio(0);                                                 \
    } while (0)

    for (int i = 0; i < NT2; ++i) {
        const int Tb = 2 * i + 1;
        const bool more = (i + 1 < NT2);

        #pragma unroll
        for (int fm = 0; fm < 8; fm++) af[fm] = RDA(0, fm, 0);
        #pragma unroll
        for (int fn = 0; fn < 4; fn++) b0[fn] = RDB(0, fn, 0);
        SH(Tb, 0, 1);
        BARRIER(); LGKM0();
        MFMA_BLK(0, 1, b0);
        BARRIER();

        #pragma unroll
        for (int fn = 0; fn < 4; fn++) b1[fn] = RDB(0, fn, 1);
        SH(Tb, 1, 1);
        BARRIER(); LGKM0();
        MFMA_BLK(2, 3, b0);
        BARRIER();

        #pragma unroll
        for (int fm = 0; fm < 8; fm++) af[fm] = RDA(0, fm, 1);
        if (more) SH(Tb + 1, 1, 0);
        BARRIER(); LGKM0();
        MFMA_BLK(0, 1, b1);
        BARRIER();

        if (more) SH(Tb + 1, 0, 0);
        BARRIER(); LGKM0();
        MFMA_BLK(2, 3, b1);
        if (more) asm volatile("s_waitcnt vmcnt(4)" ::: "memory");
        else      asm volatile("s_waitcnt vmcnt(0)" ::: "memory");
        BARRIER();

        #pragma unroll
        for (int fm = 0; fm < 8; fm++) af[fm] = RDA(1, fm, 0);
        #pragma unroll
        for (int fn = 0; fn < 4; fn++) b0[fn] = RDB(1, fn, 0);
        if (more) SH(Tb + 1, 0, 1);
        BARRIER(); LGKM0();
        MFMA_BLK(0, 1, b0);
        BARRIER();

        #pragma unroll
        for (int fn = 0; fn < 4; fn++) b1[fn] = RDB(1, fn, 1);
        if (more) SH(Tb + 1, 1, 1);
        BARRIER(); LGKM0();
        MFMA_BLK(2, 3, b0);
        BARRIER();

        #pragma unroll
        for (int fm = 0; fm < 8; fm++) af[fm] = RDA(1, fm, 1);
        if (more) SH(Tb + 2, 1, 0);
        BARRIER(); LGKM0();
        MFMA_BLK(0, 1, b1);
        BARRIER();

        if (more) SH(Tb + 2, 0, 0);
        BARRIER(); LGKM0();
        MFMA_BLK(2, 3, b1);
        if (more) {
            asm volatile("s_waitcnt vmcnt(4)" ::: "memory");
            BARRIER();
        }
    }
    #undef MFMA_BLK

    const int z = n0g >> 11;
    unsigned short* Cz = CbBase + (size_t)z * Mv * Dv;
    const int ncl = (n0g & 2047) + wn * 64;
    #pragma unroll
    for (int fm = 0; fm < 8; fm++)
        #pragma unroll
        for (int fn = 0; fn < 4; fn++) {
            int row = m0 + wm * 128 + fm * 16 + lg * 4;
            int col = ncl + fn * 16 + lr;
            #pragma unroll
            for (int r = 0; r < 4; r++)
                Cz[(size_t)(row + r) * Dv + col] = bf16_rne(acc[fm][fn][r]);
        }
}

// ---------------- kernel 3b/5: ring GEMM, 128x256 tile, N=2048, 256 blocks ----------------
template<int FOUT>
__global__ __launch_bounds__(512, 2) void gemm8_kernel(
    const unsigned short* __restrict__ A,
    const unsigned short* __restrict__ WtBase,
    unsigned short* __restrict__ Cb,
    float* __restrict__ Cf,
    const float* __restrict__ bias)
{
    extern __shared__ unsigned short lds[];
    const int tid = threadIdx.x;
    const int wv = tid >> 6, ln = tid & 63;
    const int lr = ln & 15, lg = ln >> 4;
    const int wm = wv >> 2, wn = wv & 3;

    const int bid = blockIdx.x;
    const int xcd = bid & 7, idx = bid >> 3;
    const int n_idx = xcd;
    const int m_idx = idx;
    const int m0 = m_idx * 128;
    const int n0g = n_idx * 256;
    const int NT = Dv / 64;

    const int srow = ln >> 3;
    const int swz = ((ln & 7) ^ srow) << 3;
    const unsigned short* Ab = A      + (size_t)(m0  + wv * 8 + srow) * Dv + swz;
    const unsigned short* Bb = WtBase + (size_t)(n0g + wv * 8 + srow) * Dv + swz;

    auto STAGE_A = [&](int t, int d) {
        const unsigned short* g = Ab + t * 64;
        #pragma unroll
        for (int j = 0; j < 2; ++j)
            gload16(g + (size_t)(j * 64) * Dv, &lds[d * 24576 + (j * 64 + wv * 8) * 64]);
    };
    auto STAGE_B = [&](int t, int d) {
        const unsigned short* g = Bb + t * 64;
        #pragma unroll
        for (int j = 0; j < 4; ++j)
            gload16(g + (size_t)(j * 64) * Dv, &lds[d * 24576 + 8192 + (j * 64 + wv * 8) * 64]);
    };

    const int aro = (wm * 64 + lr) * 64;
    const int bro = (wn * 64 + lr) * 64;
    const int ach0 = ((lg ^ (lr & 7)) << 3);
    const int ach1 = (((4 + lg) ^ (lr & 7)) << 3);

    f32x4 acc[4][4];
    #pragma unroll
    for (int mi = 0; mi < 4; mi++)
        #pragma unroll
        for (int ni = 0; ni < 4; ni++)
            acc[mi][ni] = (f32x4){0.f, 0.f, 0.f, 0.f};

    STAGE_A(0, 0); STAGE_B(0, 0);
    STAGE_A(1, 1); STAGE_B(1, 1);
    asm volatile("s_waitcnt vmcnt(6)" ::: "memory");
    BARRIER();

    for (int t = 0; t < NT; ++t) {
        const int d = t % 3, d2 = (t + 2) % 3;
        const unsigned short* la = &lds[d * 24576];
        const unsigned short* lb = &lds[d * 24576 + 8192];

        short8 af[4][2], bf0[2][2];
        #pragma unroll
        for (int mi = 0; mi < 4; mi++) {
            af[mi][0] = *(const short8*)&la[aro + mi * 1024 + ach0];
            af[mi][1] = *(const short8*)&la[aro + mi * 1024 + ach1];
        }
        #pragma unroll
        for (int ni = 0; ni < 2; ni++) {
            bf0[ni][0] = *(const short8*)&lb[bro + ni * 1024 + ach0];
            bf0[ni][1] = *(const short8*)&lb[bro + ni * 1024 + ach1];
        }
        if (t + 2 < NT) STAGE_A(t + 2, d2);
        BARRIER();
        __builtin_amdgcn_s_setprio(1);
        #pragma unroll
        for (int mi = 0; mi < 4; mi++)
            #pragma unroll
            for (int ni = 0; ni < 2; ni++) {
                acc[mi][ni] = __builtin_amdgcn_mfma_f32_16x16x32_bf16(af[mi][0], bf0[ni][0], acc[mi][ni], 0, 0, 0);
                acc[mi][ni] = __builtin_amdgcn_mfma_f32_16x16x32_bf16(af[mi][1], bf0[ni][1], acc[mi][ni], 0, 0, 0);
            }
        __builtin_amdgcn_s_setprio(0);

        short8 bf1[2][2];
        #pragma unroll
        for (int ni = 0; ni < 2; ni++) {
            bf1[ni][0] = *(const short8*)&lb[bro + (ni + 2) * 1024 + ach0];
            bf1[ni][1] = *(const short8*)&lb[bro + (ni + 2) * 1024 + ach1];
        }
        if (t + 2 < NT) STAGE_B(t + 2, d2);
        asm volatile("s_waitcnt vmcnt(6)" ::: "memory");
        BARRIER();
        __builtin_amdgcn_s_setprio(1);
        #pragma unroll
        for (int mi = 0; mi < 4; mi++)
            #pragma unroll
            for (int ni = 0; ni < 2; ni++) {
                acc[mi][ni + 2] = __builtin_amdgcn_mfma_f32_16x16x32_bf16(af[mi][0], bf1[ni][0], acc[mi][ni + 2], 0, 0, 0);
                acc[mi][ni + 2] = __builtin_amdgcn_mfma_f32_16x16x32_bf16(af[mi][1], bf1[ni][1], acc[mi][ni + 2], 0, 0, 0);
            }
        __builtin_amdgcn_s_setprio(0);
    }

    #pragma unroll
    for (int mi = 0; mi < 4; mi++)
        #pragma unroll
        for (int ni = 0; ni < 4; ni++) {
            int row = m0 + wm * 64 + mi * 16 + lg * 4;
            int col = n0g + wn * 64 + ni * 16 + lr;
            if (FOUT) {
                float bv = bias[col];
                #pragma unroll
                for (int r = 0; r < 4; r++)
                    Cf[(size_t)(row + r) * Dv + col] = acc[mi][ni][r] + bv;
            } else {
                #pragma unroll
                for (int r = 0; r < 4; r++)
                    Cb[(size_t)(row + r) * Dv + col] = bf16_rne(acc[mi][ni][r]);
            }
        }
}

// ---------------- kernel 4: causal flash attention, 32x32 MFMA, 4 waves x 32 q-rows ----------------
// 512 blocks (32 bh x 16 q-tiles, heavy-first), 256 thr. Swapped QK^T:
// S^T C-layout: col=q=lane&31, row=kv=(reg&3)+8*(reg>>2)+4*(lane>>5).
// LDS reads per block-tile halved vs 16x16 version (32x32x16 = 2x FLOP per b128).
__global__ __launch_bounds__(256) void attn_kernel(
    const unsigned short* __restrict__ Q, const unsigned short* __restrict__ K,
    const unsigned short* __restrict__ VT, const int* __restrict__ pmask,
    unsigned short* __restrict__ CTX)
{
    __shared__ unsigned short lK[2][64 * 128];    // [kv][d], 256B rows, swz ch^(row&7)
    __shared__ unsigned short lVt[2][128 * 64];   // [d][kv], 128B rows, swz ch^(row&7)
    __shared__ int lPmB[2][64];
    __shared__ int lPmOk[2];

    const int tid = threadIdx.x, wv = tid >> 6, ln = tid & 63;
    const int lq = ln & 31, lh = ln >> 5;
    const int L = blockIdx.x;
    const int bh = (L & 7) * 4 + ((L >> 3) & 3);
    const int b = bh >> 4, h = bh & 15;
    const int v = L >> 5;
    const int qidx = (v < 8) ? (15 - v) : (v - 8);
    const int q0 = qidx * 128;
    const int qw0 = q0 + wv * 32;
    const int qg = qw0 + lq;
    const size_t hoff  = (size_t)b * Sv * Dv + (size_t)h * HDv;
    const size_t vtoff = ((size_t)b * Dv + (size_t)h * HDv) * Sv;

    // Q B-fragments (32x32x16): lane holds Q[qg][ds*16 + lh*8 + j]
    short8 qf[8];
    #pragma unroll
    for (int ds = 0; ds < 8; ds++)
        qf[ds] = *(const short8*)&Q[hoff + (size_t)qg * Dv + ds * 16 + lh * 8];

    size_t koff[4], voff[4];
    #pragma unroll
    for (int ii = 0; ii < 4; ++ii) {
        int slot = ii * 256 + tid;
        int krow = slot >> 4, kch = slot & 15;          // K: 64 rows x 16 chunks
        koff[ii] = hoff + (size_t)krow * Dv + ((kch ^ (krow & 7)) << 3);
        int vrow = slot >> 3, vch = slot & 7;           // VT: 128 rows x 8 chunks
        voff[ii] = vtoff + (size_t)vrow * Sv + ((vch ^ (vrow & 7)) << 3);
    }

    auto STAGE = [&](int t, int buf) {
        const size_t kadd = (size_t)(t << 6) * Dv;
        const int vadd = t << 6;
        unsigned short* kb = &lK[buf][0];
        unsigned short* vb = &lVt[buf][0];
        #pragma unroll
        for (int ii = 0; ii < 4; ++ii) {
            gload16(K + koff[ii] + kadd, kb + (ii * 256 + wv * 64) * 8);
            gload16(VT + voff[ii] + vadd, vb + (ii * 256 + wv * 64) * 8);
        }
        if (wv == 0) {
            int pmv = pmask[b * Sv + (t << 6) + ln];
            lPmB[buf][ln] = pmv;
            unsigned long long bal = __ballot(pmv != 0);
            if (ln == 0) lPmOk[buf] = (bal == ~0ull) ? 1 : 0;
        }
    };

    f32x16 acc[4];
    #pragma unroll
    for (int db = 0; db < 4; db++)
        #pragma unroll
        for (int e = 0; e < 16; e++) acc[db][e] = 0.f;

    float mrow = -3.0e38f, lrow = 0.f;
    const float CS = 0.12751744f;               // (1/sqrt(128)) * log2(e)
    const int nt = (q0 >> 6) + 2;
    const int pl = ln ^ 32;                     // partner lane for P exchange
    const bool hi = (lh == 1);

    auto TILE = [&](int t, int buf, auto DIAG_c) {
        constexpr bool DIAG = decltype(DIAG_c)::value;
        const int kv0 = t << 6;
        const unsigned short* kb = &lK[buf][0];
        const unsigned short* vb = &lVt[buf][0];

        // QK^T: st[kvb] = sum_ds mfma32(K-frag, Q-frag)
        f32x16 st[2];
        #pragma unroll
        for (int kvb = 0; kvb < 2; ++kvb)
            #pragma unroll
            for (int e = 0; e < 16; e++) st[kvb][e] = 0.f;

        __builtin_amdgcn_s_setprio(1);
        #pragma unroll
        for (int kvb = 0; kvb < 2; ++kvb) {
            const int krow = kvb * 32 + lq;
            const int r7 = krow & 7;
            #pragma unroll
            for (int ds = 0; ds < 8; ++ds) {
                short8 kf = *(const short8*)&kb[krow * 128 + (((ds * 2 + lh) ^ r7) << 3)];
                st[kvb] = __builtin_amdgcn_mfma_f32_32x32x16_bf16(kf, qf[ds], st[kvb], 0, 0, 0);
            }
        }
        __builtin_amdgcn_s_setprio(0);

        // softmax over lane-local 32 p-values (q = qg); combine with partner via shfl(32)
        float pv[2][16];
        float rmax;
        if constexpr (DIAG) {
            const int* pm = &lPmB[buf][0];
            #pragma unroll
            for (int kvb = 0; kvb < 2; ++kvb)
                #pragma unroll
                for (int e = 0; e < 16; ++e) {
                    int kvl = kvb * 32 + (e & 3) + 8 * (e >> 2) + 4 * lh;
                    bool ok = ((kv0 + kvl) <= qg) && (pm[kvl] != 0);
                    pv[kvb][e] = ok ? st[kvb][e] * CS : -1.0e30f;
                }
            rmax = pv[0][0];
            #pragma unroll
            for (int kvb = 0; kvb < 2; ++kvb)
                #pragma unroll
                for (int e = 0; e < 16; ++e) rmax = fmaxf(rmax, pv[kvb][e]);
            rmax = fmaxf(rmax, __shfl_xor(rmax, 32, 64));
        } else {
            rmax = st[0][0];
            #pragma unroll
            for (int kvb = 0; kvb < 2; ++kvb)
                #pragma unroll
                for (int e = 0; e < 16; ++e) rmax = fmaxf(rmax, st[kvb][e]);
            rmax = fmaxf(rmax, __shfl_xor(rmax, 32, 64));
            rmax *= CS;
        }

        if (!__all(rmax - mrow <= 8.0f)) {     // T13 defer-max
            float mn = fmaxf(mrow, rmax);
            float alpha = exp2f(mrow - mn);
            mrow = mn;
            lrow *= alpha;
            #pragma unroll
            for (int db = 0; db < 4; db++) acc[db] *= alpha;
        }

        float psum = 0.f;
        if constexpr (DIAG) {
            #pragma unroll
            for (int kvb = 0; kvb < 2; ++kvb)
                #pragma unroll
                for (int e = 0; e < 16; ++e) {
                    float ex = exp2f(pv[kvb][e] - mrow);
                    pv[kvb][e] = (pv[kvb][e] > -5.0e29f) ? ex : 0.f;
                    psum += pv[kvb][e];
                }
        } else {
            if (lPmOk[buf]) {
                #pragma unroll
                for (int kvb = 0; kvb < 2; ++kvb)
                    #pragma unroll
                    for (int e = 0; e < 16; ++e) {
                        pv[kvb][e] = exp2f(fmaf(st[kvb][e], CS, -mrow));
                        psum += pv[kvb][e];
                    }
            } else {
                const int* pm = &lPmB[buf][0];
                #pragma unroll
                for (int kvb = 0; kvb < 2; ++kvb)
                    #pragma unroll
                    for (int e = 0; e < 16; ++e) {
                        int kvl = kvb * 32 + (e & 3) + 8 * (e >> 2) + 4 * lh;
                        float ex = exp2f(fmaf(st[kvb][e], CS, -mrow));
                        pv[kvb][e] = (pm[kvl] != 0) ? ex : 0.f;
                        psum += pv[kvb][e];
                    }
            }
        }
        psum += __shfl_xor(psum, 32, 64);
        lrow += psum;

        // pack + partner exchange -> PV B-fragments pf[kvb*2 + kb16]
        PU pf[4];
        #pragma unroll
        for (int kvb = 0; kvb < 2; ++kvb) {
            uint32_t a0 = cvt_pk_bf16(pv[kvb][0],  pv[kvb][1]);
            uint32_t a1 = cvt_pk_bf16(pv[kvb][2],  pv[kvb][3]);
            uint32_t b0 = cvt_pk_bf16(pv[kvb][4],  pv[kvb][5]);
            uint32_t b1 = cvt_pk_bf16(pv[kvb][6],  pv[kvb][7]);
            uint32_t c0 = cvt_pk_bf16(pv[kvb][8],  pv[kvb][9]);
            uint32_t c1 = cvt_pk_bf16(pv[kvb][10], pv[kvb][11]);
            uint32_t d0 = cvt_pk_bf16(pv[kvb][12], pv[kvb][13]);
            uint32_t d1 = cvt_pk_bf16(pv[kvb][14], pv[kvb][15]);
            uint32_t pa0 = (uint32_t)__shfl((int)a0, pl, 64), pa1 = (uint32_t)__shfl((int)a1, pl, 64);
            uint32_t pb0 = (uint32_t)__shfl((int)b0, pl, 64), pb1 = (uint32_t)__shfl((int)b1, pl, 64);
            uint32_t pc0 = (uint32_t)__shfl((int)c0, pl, 64), pc1 = (uint32_t)__shfl((int)c1, pl, 64);
            uint32_t pd0 = (uint32_t)__shfl((int)d0, pl, 64), pd1 = (uint32_t)__shfl((int)d1, pl, 64);
            pf[kvb * 2 + 0].u[0] = hi ? pb0 : a0;
            pf[kvb * 2 + 0].u[1] = hi ? pb1 : a1;
            pf[kvb * 2 + 0].u[2] = hi ? b0 : pa0;
            pf[kvb * 2 + 0].u[3] = hi ? b1 : pa1;
            pf[kvb * 2 + 1].u[0] = hi ? pd0 : c0;
            pf[kvb * 2 + 1].u[1] = hi ? pd1 : c1;
            pf[kvb * 2 + 1].u[2] = hi ? d0 : pc0;
            pf[kvb * 2 + 1].u[3] = hi ? d1 : pc1;
        }

        // PV: ctx^T += V^T @ P^T  (A = VT rows, B = P-frags); 16 mfma32 per wave
        __builtin_amdgcn_s_setprio(1);
        #pragma unroll
        for (int db = 0; db < 4; ++db) {
            const int vrow = db * 32 + lq;
            const int r7 = vrow & 7;
            #pragma unroll
            for (int kb = 0; kb < 4; ++kb) {
                short8 vf = *(const short8*)&vb[vrow * 64 + (((kb * 2 + lh) ^ r7) << 3)];
                acc[db] = __builtin_amdgcn_mfma_f32_32x32x16_bf16(vf, pf[kb].s, acc[db], 0, 0, 0);
            }
        }
        __builtin_amdgcn_s_setprio(0);
    };

    STAGE(0, 0);
    __syncthreads();
    int cur = 0;

    using TrueC  = std::integral_constant<bool, true>;
    using FalseC = std::integral_constant<bool, false>;

    for (int t = 0; t < nt; ++t) {
        if (t + 1 < nt) STAGE(t + 1, cur ^ 1);
        const int kv0 = t << 6;
        if (kv0 <= qw0 + 31) {                 // wave-uniform: skip fully-masked tiles
            if (kv0 + 63 > qw0) TILE(t, cur, TrueC{});
            else                TILE(t, cur, FalseC{});
        }
        __syncthreads();
        cur ^= 1;
    }

    // epilogue: d = db*32 + (e&3) + 8*(e>>2) + 4*lh -> quads of 4 consecutive d (8B stores)
    float inv = 1.0f / lrow;
    #pragma unroll
    for (int db = 0; db < 4; ++db)
        #pragma unroll
        for (int q2 = 0; q2 < 4; ++q2) {
            short4v o;
            #pragma unroll
            for (int r = 0; r < 4; r++) o[r] = (short)bf16_rne(acc[db][q2 * 4 + r] * inv);
            *(short4v*)&CTX[hoff + (size_t)qg * Dv + db * 32 + q2 * 8 + lh * 4] = o;
        }
}

// ---------------- launcher ----------------
extern "C" void kernel_launch(void* const* d_in, const int* in_sizes, int n_in,
                              void* d_out, int out_size, void* d_ws, size_t ws_size,
                              hipStream_t stream) {
    const float* hs  = (const float*)d_in[0];
    const int*   am  = (const int*)d_in[1];
    const float* wq  = (const float*)d_in[2];
    const float* wk  = (const float*)d_in[3];
    const float* wv_ = (const float*)d_in[4];
    const float* wo  = (const float*)d_in[5];
    const float* bo  = (const float*)d_in[6];
    float* out = (float*)d_out;

    char* ws = (char*)d_ws;
    unsigned short* Xb  = (unsigned short*)ws;                               // 16 MiB: X bf16; later VT
    unsigned short* Wt  = (unsigned short*)(ws + (size_t)16 * 1024 * 1024);  // 32 MiB: 4x Wt bf16
    unsigned short* QKV = (unsigned short*)(ws + (size_t)48 * 1024 * 1024);  // 48 MiB: Q,K,V bf16
    unsigned short* CTX = (unsigned short*)(ws + (size_t)96 * 1024 * 1024);  // 16 MiB: ctx bf16
    unsigned short* VT  = Xb;                                                // alias (Xb dead after projections)

    const int LDSB_8PH = 131072;      // 128 KiB dynamic LDS
    const int LDSB_R   = 147456;      // 144 KiB dynamic LDS
    static bool attrSet = false;
    if (!attrSet) {
        hipFuncSetAttribute((const void*)gemm8ph_kernel, hipFuncAttributeMaxDynamicSharedMemorySize, LDSB_8PH);
        hipFuncSetAttribute((const void*)gemm8_kernel<0>, hipFuncAttributeMaxDynamicSharedMemorySize, LDSB_R);
        hipFuncSetAttribute((const void*)gemm8_kernel<1>, hipFuncAttributeMaxDynamicSharedMemorySize, LDSB_R);
        attrSet = true;
    }

    hipLaunchKernelGGL(cvt_x_kernel, dim3(Mv * Dv / 4 / 256), dim3(256), 0, stream, hs, Xb);
    hipLaunchKernelGGL(cvt_wt_kernel, dim3(32, 32, 4), dim3(256), 0, stream, wq, wk, wv_, wo, Wt);
    // QK projection: 8-phase 256^2, N=4096 (wq,wk), 256 blocks = 1 exact CU round
    hipLaunchKernelGGL(gemm8ph_kernel, dim3(256), dim3(512), LDSB_8PH, stream, Xb, Wt, QKV);
    // V projection: ring gemm, N=2048 (wv), 256 blocks = 1 exact CU round, bf16 out
    hipLaunchKernelGGL(gemm8_kernel<0>, dim3(256), dim3(512), LDSB_R, stream,
                       Xb, Wt + 2 * (size_t)Dv * Dv, QKV + 2 * (size_t)Mv * Dv, (float*)nullptr, (const float*)nullptr);
    hipLaunchKernelGGL(vt_kernel, dim3(32, 32, 2), dim3(256), 0, stream,
                       QKV + 2 * (size_t)Mv * Dv, VT);
    // attention: 32x32 MFMA, 4 waves x 32 q-rows, 512 blocks (2/CU)
    hipLaunchKernelGGL(attn_kernel, dim3(512), dim3(256), 0, stream,
                       QKV, QKV + (size_t)Mv * Dv, VT, am, CTX);
    // out-proj: N=2048, 256 blocks = 1 exact CU round, fp32 + bias
    hipLaunchKernelGGL(gemm8_kernel<1>, dim3(256), dim3(512), LDSB_R, stream,
                       CTX, Wt + 3 * (size_t)Dv * Dv, (unsigned short*)nullptr, out, bo);
}

// Round 13
// 236.599 us; speedup vs baseline: 1.1881x; 1.1881x over previous
//
#include <hip/hip_runtime.h>
#include <hip/hip_bf16.h>
#include <stdint.h>

// Problem constants (FlaxGPTNeoSelfAttention): B=2, S=2048, D=2048, H=16, HD=128
#define Bv 2
#define Sv 2048
#define Dv 2048
#define Hv 16
#define HDv 128
#define Mv (Bv*Sv)   // 4096 rows for the projection GEMMs

typedef __attribute__((ext_vector_type(8))) short short8;
typedef __attribute__((ext_vector_type(4))) short short4v;
typedef __attribute__((ext_vector_type(4))) float f32x4;

__device__ __forceinline__ unsigned short bf16_rne(float f) {
    union { float f; uint32_t u; } c; c.f = f;
    uint32_t u = c.u;
    u += 0x7fffu + ((u >> 16) & 1u);   // round-to-nearest-even
    return (unsigned short)(u >> 16);
}

__device__ __forceinline__ uint32_t cvt_pk_bf16(float lo, float hi) {
    uint32_t r;
    asm("v_cvt_pk_bf16_f32 %0, %1, %2" : "=v"(r) : "v"(lo), "v"(hi));
    return r;
}

__device__ __forceinline__ void gload16(const void* g, void* l) {
    // async global->LDS, 16B per lane; LDS dest = wave-uniform base + lane*16
    __builtin_amdgcn_global_load_lds((const __attribute__((address_space(1))) void*)g,
                                     (__attribute__((address_space(3))) void*)l, 16, 0, 0);
}

#define BARRIER() asm volatile("s_barrier" ::: "memory")
#define LGKM0()   do { asm volatile("s_waitcnt lgkmcnt(0)" ::: "memory"); \
                       __builtin_amdgcn_sched_barrier(0); } while (0)

// ---------------- kernel 1: hidden_states fp32 -> bf16 (16B loads, 16B stores) ----------------
__global__ void cvt_x_kernel(const float* __restrict__ x, unsigned short* __restrict__ xb) {
    int i = (blockIdx.x * 256 + threadIdx.x) * 8;
    float4 v0 = *(const float4*)(x + i);
    float4 v1 = *(const float4*)(x + i + 4);
    short8 o;
    o[0] = (short)bf16_rne(v0.x); o[1] = (short)bf16_rne(v0.y);
    o[2] = (short)bf16_rne(v0.z); o[3] = (short)bf16_rne(v0.w);
    o[4] = (short)bf16_rne(v1.x); o[5] = (short)bf16_rne(v1.y);
    o[6] = (short)bf16_rne(v1.z); o[7] = (short)bf16_rne(v1.w);
    *(short8*)(xb + i) = o;
}

// ---------------- kernel 2: weights fp32 -> bf16, transposed Wt[n][k] (vectorized) ----------------
__global__ void cvt_wt_kernel(const float* __restrict__ w0, const float* __restrict__ w1,
                              const float* __restrict__ w2, const float* __restrict__ w3,
                              unsigned short* __restrict__ wt) {
    __shared__ unsigned short t[64 * 65];   // t[kk][nn], padded
    const int tid = threadIdx.x;
    int z = blockIdx.z;
    const float* w = (z == 0) ? w0 : (z == 1) ? w1 : (z == 2) ? w2 : w3;
    unsigned short* o = wt + (size_t)z * Dv * Dv;
    int k0 = blockIdx.x * 64, n0 = blockIdx.y * 64;
    // read: float4 per thread x 4 rows
    #pragma unroll
    for (int j = 0; j < 4; ++j) {
        int r = (tid >> 4) + j * 16;         // kk
        int c = (tid & 15) * 4;              // nn
        float4 v = *(const float4*)&w[(size_t)(k0 + r) * Dv + n0 + c];
        t[r * 65 + c + 0] = bf16_rne(v.x);
        t[r * 65 + c + 1] = bf16_rne(v.y);
        t[r * 65 + c + 2] = bf16_rne(v.z);
        t[r * 65 + c + 3] = bf16_rne(v.w);
    }
    __syncthreads();
    // write: short8 (16B) per thread x 2 — gather 8 kk for one nn
    #pragma unroll
    for (int j = 0; j < 2; ++j) {
        int flat = tid + j * 256;
        int nn = flat >> 3;                  // 0..63
        int kk = (flat & 7) * 8;
        short8 v;
        #pragma unroll
        for (int e = 0; e < 8; ++e) v[e] = (short)t[(kk + e) * 65 + nn];
        *(short8*)&o[(size_t)(n0 + nn) * Dv + k0 + kk] = v;
    }
}

// ---------------- kernel 2b: V (bf16 [4096][2048]) -> VT per batch ([b*2048+c][s]) ----------------
__global__ void vt_kernel(const unsigned short* __restrict__ V, unsigned short* __restrict__ VT) {
    __shared__ unsigned short t[64 * 64];   // XOR chunk-swizzled 64x64 tile
    const int tid = threadIdx.x;
    const int b = blockIdx.z;
    const int s0 = blockIdx.x * 64, c0 = blockIdx.y * 64;
    const unsigned short* Vb = V + (size_t)b * Sv * Dv;
    unsigned short* VTb = VT + (size_t)b * Dv * Sv;
    #pragma unroll
    for (int ii = 0; ii < 2; ++ii) {
        int i = tid + ii * 256;
        int r = i >> 3, ch = i & 7;
        short8 v = *(const short8*)&Vb[(size_t)(s0 + r) * Dv + c0 + ch * 8];
        *(short8*)&t[r * 64 + ((ch ^ (r & 7)) << 3)] = v;
    }
    __syncthreads();
    #pragma unroll
    for (int ii = 0; ii < 2; ++ii) {
        int o = tid + ii * 256;
        int orow = o >> 3, och = o & 7;
        short8 v;
        #pragma unroll
        for (int j = 0; j < 8; ++j) {
            int r = och * 8 + j;
            int c = orow;
            v[j] = (short)t[r * 64 + ((((c >> 3) ^ (r & 7)) << 3) | (c & 7))];
        }
        *(short8*)&VTb[(size_t)(c0 + orow) * Sv + s0 + och * 8] = v;
    }
}

// ---------------- kernel 3a: QK projection, 8-phase 256x256 (R6 kernel, balanced 256-block grid) ----------------
__global__ __launch_bounds__(512, 2) void gemm8ph_kernel(
    const unsigned short* __restrict__ A,
    const unsigned short* __restrict__ WtBase,
    unsigned short* __restrict__ CbBase)
{
    extern __shared__ unsigned short lds[];   // 65536 shorts = 128 KiB
    const int tid = threadIdx.x;
    const int wv = tid >> 6, ln = tid & 63;
    const int lr = ln & 15, lg = ln >> 4;
    const int wm = wv >> 2, wn = wv & 3;      // 2 x 4 waves

    const int bid = blockIdx.x;
    const int xcd = bid & 7, idx = bid >> 3;
    const int n_idx = xcd * 2 + idx / 16;     // 0..15
    const int m_idx = idx % 16;
    const int m0 = m_idx * 256, n0g = n_idx * 256;

    const int lrow = wv * 8 + (ln >> 3);
    const int lcol = ((ln & 7) ^ (ln >> 3)) << 3;
    const unsigned short* Ag = A      + (size_t)(m0  + lrow) * Dv + lcol;
    const unsigned short* Bg = WtBase + (size_t)(n0g + lrow) * Dv + lcol;

    auto SH = [&](int T, int isB, int h) {
        const unsigned short* src = (isB ? Bg : Ag) + (size_t)(h * 128) * Dv + T * 64;
        unsigned short* dst = &lds[(T & 1) * 32768 + isB * 16384 + h * 8192 + wv * 512];
        gload16(src, dst);
        gload16(src + (size_t)64 * Dv, dst + 4096);
    };

    const int axk = lr & 7;
    auto RDA = [&](int buf, int fm, int ks) {
        return *(const short8*)&lds[buf * 32768 + (wm * 128 + fm * 16 + lr) * 64 + (((ks * 4 + lg) ^ axk) << 3)];
    };
    auto RDB = [&](int buf, int fn, int ks) {
        return *(const short8*)&lds[buf * 32768 + 16384 + (wn * 64 + fn * 16 + lr) * 64 + (((ks * 4 + lg) ^ axk) << 3)];
    };

    f32x4 acc[8][4];
    #pragma unroll
    for (int fm = 0; fm < 8; fm++)
        #pragma unroll
        for (int fn = 0; fn < 4; fn++)
            acc[fm][fn] = (f32x4){0.f, 0.f, 0.f, 0.f};

    // prologue: T0 full (4 halves), then T1.B0, T1.A0 (matches steady-state lag)
    SH(0, 0, 0); SH(0, 0, 1); SH(0, 1, 0); SH(0, 1, 1);
    SH(1, 1, 0); SH(1, 0, 0);
    asm volatile("s_waitcnt vmcnt(4)" ::: "memory");
    BARRIER();

    short8 af[8], b0[4], b1[4];
    const int NT2 = 16;                        // 32 K-tiles, 2 per iteration

    #define MFMA_BLK(FN0, FN1, BARR) do {                                              \
        __builtin_amdgcn_s_setprio(1);                                                 \
        _Pragma("unroll")                                                              \
        for (int fm = 0; fm < 8; fm++) {                                               \
            acc[fm][FN0] = __builtin_amdgcn_mfma_f32_16x16x32_bf16(af[fm], BARR[FN0], acc[fm][FN0], 0, 0, 0); \
            acc[fm][FN1] = __builtin_amdgcn_mfma_f32_16x16x32_bf16(af[fm], BARR[FN1], acc[fm][FN1], 0, 0, 0); \
        }                                                                              \
        __builtin_amdgcn_s_setprio(0);                                                 \
    } while (0)

    for (int i = 0; i < NT2; ++i) {
        const int Tb = 2 * i + 1;
        const bool more = (i + 1 < NT2);

        // ======== group A: tile 2i in buf0 ========
        #pragma unroll
        for (int fm = 0; fm < 8; fm++) af[fm] = RDA(0, fm, 0);
        #pragma unroll
        for (int fn = 0; fn < 4; fn++) b0[fn] = RDB(0, fn, 0);
        SH(Tb, 0, 1);
        BARRIER(); LGKM0();
        MFMA_BLK(0, 1, b0);
        BARRIER();

        #pragma unroll
        for (int fn = 0; fn < 4; fn++) b1[fn] = RDB(0, fn, 1);
        SH(Tb, 1, 1);
        BARRIER(); LGKM0();
        MFMA_BLK(2, 3, b0);
        BARRIER();

        #pragma unroll
        for (int fm = 0; fm < 8; fm++) af[fm] = RDA(0, fm, 1);
        if (more) SH(Tb + 1, 1, 0);
        BARRIER(); LGKM0();
        MFMA_BLK(0, 1, b1);
        BARRIER();

        if (more) SH(Tb + 1, 0, 0);
        BARRIER(); LGKM0();
        MFMA_BLK(2, 3, b1);
        if (more) asm volatile("s_waitcnt vmcnt(4)" ::: "memory");
        else      asm volatile("s_waitcnt vmcnt(0)" ::: "memory");
        BARRIER();

        // ======== group B: tile 2i+1 in buf1 ========
        #pragma unroll
        for (int fm = 0; fm < 8; fm++) af[fm] = RDA(1, fm, 0);
        #pragma unroll
        for (int fn = 0; fn < 4; fn++) b0[fn] = RDB(1, fn, 0);
        if (more) SH(Tb + 1, 0, 1);
        BARRIER(); LGKM0();
        MFMA_BLK(0, 1, b0);
        BARRIER();

        #pragma unroll
        for (int fn = 0; fn < 4; fn++) b1[fn] = RDB(1, fn, 1);
        if (more) SH(Tb + 1, 1, 1);
        BARRIER(); LGKM0();
        MFMA_BLK(2, 3, b0);
        BARRIER();

        #pragma unroll
        for (int fm = 0; fm < 8; fm++) af[fm] = RDA(1, fm, 1);
        if (more) SH(Tb + 2, 1, 0);
        BARRIER(); LGKM0();
        MFMA_BLK(0, 1, b1);
        BARRIER();

        if (more) SH(Tb + 2, 0, 0);
        BARRIER(); LGKM0();
        MFMA_BLK(2, 3, b1);
        if (more) {
            asm volatile("s_waitcnt vmcnt(4)" ::: "memory");
            BARRIER();
        }
    }
    #undef MFMA_BLK

    // epilogue: bf16 stores, z = n-panel / 8 (Q at z=0, K at z=1)
    const int z = n0g >> 11;
    unsigned short* Cz = CbBase + (size_t)z * Mv * Dv;
    const int ncl = (n0g & 2047) + wn * 64;
    #pragma unroll
    for (int fm = 0; fm < 8; fm++)
        #pragma unroll
        for (int fn = 0; fn < 4; fn++) {
            int row = m0 + wm * 128 + fm * 16 + lg * 4;
            int col = ncl + fn * 16 + lr;
            #pragma unroll
            for (int r = 0; r < 4; r++)
                Cz[(size_t)(row + r) * Dv + col] = bf16_rne(acc[fm][fn][r]);
        }
}

// ---------------- kernel 3b/5: ring GEMM (R4 proven structure), 128x256 tile, N=2048, 256 blocks ----------------
// FOUT=0: bf16 store (V projection). FOUT=1: fp32 store with +bias (out-proj).
template<int FOUT>
__global__ __launch_bounds__(512, 2) void gemm8_kernel(
    const unsigned short* __restrict__ A,
    const unsigned short* __restrict__ WtBase,
    unsigned short* __restrict__ Cb,
    float* __restrict__ Cf,
    const float* __restrict__ bias)
{
    extern __shared__ unsigned short lds[];    // 3 bufs x (A 8192 + B 16384) shorts = 144 KiB
    const int tid = threadIdx.x;
    const int wv = tid >> 6, ln = tid & 63;
    const int lr = ln & 15, lg = ln >> 4;
    const int wm = wv >> 2, wn = wv & 3;

    const int bid = blockIdx.x;
    const int xcd = bid & 7, idx = bid >> 3;
    const int n_idx = xcd;                     // 8 n-panels, 1 per XCD
    const int m_idx = idx;                     // 32 m-panels
    const int m0 = m_idx * 128;
    const int n0g = n_idx * 256;
    const int NT = Dv / 64;

    const int srow = ln >> 3;
    const int swz = ((ln & 7) ^ srow) << 3;
    const unsigned short* Ab = A      + (size_t)(m0  + wv * 8 + srow) * Dv + swz;
    const unsigned short* Bb = WtBase + (size_t)(n0g + wv * 8 + srow) * Dv + swz;

    auto STAGE_A = [&](int t, int d) {
        const unsigned short* g = Ab + t * 64;
        #pragma unroll
        for (int j = 0; j < 2; ++j)
            gload16(g + (size_t)(j * 64) * Dv, &lds[d * 24576 + (j * 64 + wv * 8) * 64]);
    };
    auto STAGE_B = [&](int t, int d) {
        const unsigned short* g = Bb + t * 64;
        #pragma unroll
        for (int j = 0; j < 4; ++j)
            gload16(g + (size_t)(j * 64) * Dv, &lds[d * 24576 + 8192 + (j * 64 + wv * 8) * 64]);
    };

    const int aro = (wm * 64 + lr) * 64;
    const int bro = (wn * 64 + lr) * 64;
    const int ach0 = ((lg ^ (lr & 7)) << 3);
    const int ach1 = (((4 + lg) ^ (lr & 7)) << 3);

    f32x4 acc[4][4];
    #pragma unroll
    for (int mi = 0; mi < 4; mi++)
        #pragma unroll
        for (int ni = 0; ni < 4; ni++)
            acc[mi][ni] = (f32x4){0.f, 0.f, 0.f, 0.f};

    STAGE_A(0, 0); STAGE_B(0, 0);
    STAGE_A(1, 1); STAGE_B(1, 1);
    asm volatile("s_waitcnt vmcnt(6)" ::: "memory");
    BARRIER();

    for (int t = 0; t < NT; ++t) {
        const int d = t % 3, d2 = (t + 2) % 3;
        const unsigned short* la = &lds[d * 24576];
        const unsigned short* lb = &lds[d * 24576 + 8192];

        short8 af[4][2], bf0[2][2];
        #pragma unroll
        for (int mi = 0; mi < 4; mi++) {
            af[mi][0] = *(const short8*)&la[aro + mi * 1024 + ach0];
            af[mi][1] = *(const short8*)&la[aro + mi * 1024 + ach1];
        }
        #pragma unroll
        for (int ni = 0; ni < 2; ni++) {
            bf0[ni][0] = *(const short8*)&lb[bro + ni * 1024 + ach0];
            bf0[ni][1] = *(const short8*)&lb[bro + ni * 1024 + ach1];
        }
        if (t + 2 < NT) STAGE_A(t + 2, d2);
        BARRIER();
        __builtin_amdgcn_s_setprio(1);
        #pragma unroll
        for (int mi = 0; mi < 4; mi++)
            #pragma unroll
            for (int ni = 0; ni < 2; ni++) {
                acc[mi][ni] = __builtin_amdgcn_mfma_f32_16x16x32_bf16(af[mi][0], bf0[ni][0], acc[mi][ni], 0, 0, 0);
                acc[mi][ni] = __builtin_amdgcn_mfma_f32_16x16x32_bf16(af[mi][1], bf0[ni][1], acc[mi][ni], 0, 0, 0);
            }
        __builtin_amdgcn_s_setprio(0);

        short8 bf1[2][2];
        #pragma unroll
        for (int ni = 0; ni < 2; ni++) {
            bf1[ni][0] = *(const short8*)&lb[bro + (ni + 2) * 1024 + ach0];
            bf1[ni][1] = *(const short8*)&lb[bro + (ni + 2) * 1024 + ach1];
        }
        if (t + 2 < NT) STAGE_B(t + 2, d2);
        asm volatile("s_waitcnt vmcnt(6)" ::: "memory");
        BARRIER();
        __builtin_amdgcn_s_setprio(1);
        #pragma unroll
        for (int mi = 0; mi < 4; mi++)
            #pragma unroll
            for (int ni = 0; ni < 2; ni++) {
                acc[mi][ni + 2] = __builtin_amdgcn_mfma_f32_16x16x32_bf16(af[mi][0], bf1[ni][0], acc[mi][ni + 2], 0, 0, 0);
                acc[mi][ni + 2] = __builtin_amdgcn_mfma_f32_16x16x32_bf16(af[mi][1], bf1[ni][1], acc[mi][ni + 2], 0, 0, 0);
            }
        __builtin_amdgcn_s_setprio(0);
    }

    #pragma unroll
    for (int mi = 0; mi < 4; mi++)
        #pragma unroll
        for (int ni = 0; ni < 4; ni++) {
            int row = m0 + wm * 64 + mi * 16 + lg * 4;
            int col = n0g + wn * 64 + ni * 16 + lr;
            if (FOUT) {
                float bv = bias[col];
                #pragma unroll
                for (int r = 0; r < 4; r++)
                    Cf[(size_t)(row + r) * Dv + col] = acc[mi][ni][r] + bv;
            } else {
                #pragma unroll
                for (int r = 0; r < 4; r++)
                    Cb[(size_t)(row + r) * Dv + col] = bf16_rne(acc[mi][ni][r]);
            }
        }
}

// ---------------- kernel 4: causal flash attention (R9 proven: 512 blocks, 8 waves, 16q/wave) ----------------
__global__ __launch_bounds__(512) void attn_kernel(
    const unsigned short* __restrict__ Q, const unsigned short* __restrict__ K,
    const unsigned short* __restrict__ VT, const int* __restrict__ pmask,
    unsigned short* __restrict__ CTX)
{
    __shared__ unsigned short lK[2][64 * 128];
    __shared__ unsigned short lVt[2][128 * 64];
    __shared__ int lPmB[2][64];
    __shared__ int lPmOk[2];

    const int tid = threadIdx.x, wv = tid >> 6, ln = tid & 63;
    const int lr = ln & 15, lg = ln >> 4;
    const int L = blockIdx.x;
    const int bh = (L & 7) * 4 + ((L >> 3) & 3);
    const int b = bh >> 4, h = bh & 15;
    const int v = L >> 5;
    const int qidx = (v < 8) ? (15 - v) : (v - 8);
    const int q0 = qidx * 128;
    const int qw0 = q0 + wv * 16;
    const size_t hoff  = (size_t)b * Sv * Dv + (size_t)h * HDv;
    const size_t vtoff = ((size_t)b * Dv + (size_t)h * HDv) * Sv;

    short8 qf[4];
    #pragma unroll
    for (int ds = 0; ds < 4; ds++)
        qf[ds] = *(const short8*)&Q[hoff + (size_t)(qw0 + lr) * Dv + ds * 32 + lg * 8];

    size_t koff[2], voff[2];
    #pragma unroll
    for (int ii = 0; ii < 2; ++ii) {
        int slot = ii * 512 + wv * 64 + ln;
        int krow = slot >> 4, kch = slot & 15;
        koff[ii] = hoff + (size_t)krow * Dv + ((kch ^ (krow & 7)) << 3);
        int vrow = slot >> 3, vch = slot & 7;
        voff[ii] = vtoff + (size_t)vrow * Sv + ((vch ^ (vrow & 7)) << 3);
    }

    auto STAGE = [&](int t, int buf) {
        const size_t kadd = (size_t)(t << 6) * Dv;
        const int vadd = t << 6;
        unsigned short* kb = &lK[buf][0];
        unsigned short* vb = &lVt[buf][0];
        #pragma unroll
        for (int ii = 0; ii < 2; ++ii) {
            gload16(K + koff[ii] + kadd, kb + (ii * 512 + wv * 64) * 8);
            gload16(VT + voff[ii] + vadd, vb + (ii * 512 + wv * 64) * 8);
        }
        if (wv == 0) {
            int pmv = pmask[b * Sv + (t << 6) + ln];
            lPmB[buf][ln] = pmv;
            unsigned long long bal = __ballot(pmv != 0);
            if (ln == 0) lPmOk[buf] = (bal == ~0ull) ? 1 : 0;
        }
    };

    f32x4 acc[8];
    #pragma unroll
    for (int n = 0; n < 8; n++) acc[n] = (f32x4){0.f, 0.f, 0.f, 0.f};
    float mrow = -3.0e38f, lrow = 0.f;
    const float CS = 0.12751744f;
    const int qg = qw0 + lr;
    const int nt = (q0 >> 6) + 2;
    const int srcA = lr + ((lg & 1) << 5);
    const int srcB = srcA + 16;
    const bool hiSel = (lg >= 2);

    auto TILE = [&](int t, int buf, auto CAUSAL_c) {
        constexpr bool CAUSAL = decltype(CAUSAL_c)::value;
        const int kv0 = t << 6;
        const unsigned short* kb = &lK[buf][0];
        const unsigned short* vb = &lVt[buf][0];

        f32x4 st[4];
        #pragma unroll
        for (int t2 = 0; t2 < 4; ++t2) st[t2] = (f32x4){0.f, 0.f, 0.f, 0.f};
        __builtin_amdgcn_s_setprio(1);
        #pragma unroll
        for (int t2 = 0; t2 < 4; ++t2) {
            const int krow = t2 * 16 + lr;
            #pragma unroll
            for (int ds = 0; ds < 4; ++ds) {
                const int ch = ds * 4 + lg;
                short8 kf = *(const short8*)&kb[krow * 128 + ((ch ^ (krow & 7)) << 3)];
                st[t2] = __builtin_amdgcn_mfma_f32_16x16x32_bf16(kf, qf[ds], st[t2], 0, 0, 0);
            }
        }
        __builtin_amdgcn_s_setprio(0);

        float sv[4][4];
        float rmax;
        if constexpr (CAUSAL) {
            const int* pm = &lPmB[buf][0];
            #pragma unroll
            for (int t2 = 0; t2 < 4; ++t2)
                #pragma unroll
                for (int r = 0; r < 4; ++r) {
                    int kvl = t2 * 16 + lg * 4 + r;
                    bool ok = ((kv0 + kvl) <= qg) && (pm[kvl] != 0);
                    sv[t2][r] = ok ? st[t2][r] * CS : -1.0e30f;
                }
            rmax = sv[0][0];
            #pragma unroll
            for (int t2 = 0; t2 < 4; ++t2)
                #pragma unroll
                for (int r = 0; r < 4; ++r) rmax = fmaxf(rmax, sv[t2][r]);
            rmax = fmaxf(rmax, __shfl_xor(rmax, 16, 64));
            rmax = fmaxf(rmax, __shfl_xor(rmax, 32, 64));
        } else {
            rmax = st[0][0];
            #pragma unroll
            for (int t2 = 0; t2 < 4; ++t2)
                #pragma unroll
                for (int r = 0; r < 4; ++r) rmax = fmaxf(rmax, st[t2][r]);
            rmax = fmaxf(rmax, __shfl_xor(rmax, 16, 64));
            rmax = fmaxf(rmax, __shfl_xor(rmax, 32, 64));
            rmax *= CS;
        }

        if (!__all(rmax - mrow <= 8.0f)) {
            float mn = fmaxf(mrow, rmax);
            float alpha = exp2f(mrow - mn);
            mrow = mn;
            lrow *= alpha;
            #pragma unroll
            for (int n = 0; n < 8; n++)
                #pragma unroll
                for (int r = 0; r < 4; r++) acc[n][r] *= alpha;
        }

        float p[4][4]; float psum = 0.f;
        if constexpr (CAUSAL) {
            #pragma unroll
            for (int t2 = 0; t2 < 4; ++t2)
                #pragma unroll
                for (int r = 0; r < 4; ++r) {
                    float e = exp2f(sv[t2][r] - mrow);
                    p[t2][r] = (sv[t2][r] > -5.0e29f) ? e : 0.f;
                    psum += p[t2][r];
                }
        } else {
            if (lPmOk[buf]) {
                #pragma unroll
                for (int t2 = 0; t2 < 4; ++t2)
                    #pragma unroll
                    for (int r = 0; r < 4; ++r) {
                        p[t2][r] = exp2f(fmaf(st[t2][r], CS, -mrow));
                        psum += p[t2][r];
                    }
            } else {
                const int* pm = &lPmB[buf][0];
                #pragma unroll
                for (int t2 = 0; t2 < 4; ++t2)
                    #pragma unroll
                    for (int r = 0; r < 4; ++r) {
                        int kvl = t2 * 16 + lg * 4 + r;
                        float e = exp2f(fmaf(st[t2][r], CS, -mrow));
                        p[t2][r] = (pm[kvl] != 0) ? e : 0.f;
                        psum += p[t2][r];
                    }
            }
        }
        psum += __shfl_xor(psum, 16, 64);
        psum += __shfl_xor(psum, 32, 64);
        lrow += psum;

        uint32_t pk[4][2];
        #pragma unroll
        for (int t2 = 0; t2 < 4; ++t2)
            #pragma unroll
            for (int pp = 0; pp < 2; ++pp)
                pk[t2][pp] = cvt_pk_bf16(p[t2][2 * pp], p[t2][2 * pp + 1]);

        union U { uint32_t u[4]; short8 s; } pa0, pa1;
        {
            uint32_t l0 = (uint32_t)__shfl((int)pk[0][0], srcA, 64), h0 = (uint32_t)__shfl((int)pk[1][0], srcA, 64);
            uint32_t l1 = (uint32_t)__shfl((int)pk[0][1], srcA, 64), h1 = (uint32_t)__shfl((int)pk[1][1], srcA, 64);
            uint32_t l2 = (uint32_t)__shfl((int)pk[0][0], srcB, 64), h2 = (uint32_t)__shfl((int)pk[1][0], srcB, 64);
            uint32_t l3 = (uint32_t)__shfl((int)pk[0][1], srcB, 64), h3 = (uint32_t)__shfl((int)pk[1][1], srcB, 64);
            pa0.u[0] = hiSel ? h0 : l0; pa0.u[1] = hiSel ? h1 : l1;
            pa0.u[2] = hiSel ? h2 : l2; pa0.u[3] = hiSel ? h3 : l3;
        }
        {
            uint32_t l0 = (uint32_t)__shfl((int)pk[2][0], srcA, 64), h0 = (uint32_t)__shfl((int)pk[3][0], srcA, 64);
            uint32_t l1 = (uint32_t)__shfl((int)pk[2][1], srcA, 64), h1 = (uint32_t)__shfl((int)pk[3][1], srcA, 64);
            uint32_t l2 = (uint32_t)__shfl((int)pk[2][0], srcB, 64), h2 = (uint32_t)__shfl((int)pk[3][0], srcB, 64);
            uint32_t l3 = (uint32_t)__shfl((int)pk[2][1], srcB, 64), h3 = (uint32_t)__shfl((int)pk[3][1], srcB, 64);
            pa1.u[0] = hiSel ? h0 : l0; pa1.u[1] = hiSel ? h1 : l1;
            pa1.u[2] = hiSel ? h2 : l2; pa1.u[3] = hiSel ? h3 : l3;
        }

        __builtin_amdgcn_s_setprio(1);
        #pragma unroll
        for (int n = 0; n < 8; n++) {
            const int vrow = n * 16 + lr;
            short8 a0 = *(const short8*)&vb[vrow * 64 + ((lg ^ (vrow & 7)) << 3)];
            acc[n] = __builtin_amdgcn_mfma_f32_16x16x32_bf16(a0, pa0.s, acc[n], 0, 0, 0);
            short8 a1 = *(const short8*)&vb[vrow * 64 + (((4 + lg) ^ (vrow & 7)) << 3)];
            acc[n] = __builtin_amdgcn_mfma_f32_16x16x32_bf16(a1, pa1.s, acc[n], 0, 0, 0);
        }
        __builtin_amdgcn_s_setprio(0);
    };

    STAGE(0, 0);
    __syncthreads();
    int cur = 0;

    for (int t = 0; t < nt; ++t) {
        if (t + 1 < nt) STAGE(t + 1, cur ^ 1);
        const int kv0 = t << 6;
        if (kv0 <= qw0 + 15) {
            if (kv0 + 63 > qw0) TILE(t, cur, std::integral_constant<bool, true>{});
            else                TILE(t, cur, std::integral_constant<bool, false>{});
        }
        __syncthreads();
        cur ^= 1;
    }

    float inv = 1.0f / lrow;
    #pragma unroll
    for (int n = 0; n < 8; n++) {
        short4v o;
        #pragma unroll
        for (int r = 0; r < 4; r++) o[r] = (short)bf16_rne(acc[n][r] * inv);
        *(short4v*)&CTX[hoff + (size_t)qg * Dv + n * 16 + lg * 4] = o;
    }
}

// ---------------- launcher ----------------
extern "C" void kernel_launch(void* const* d_in, const int* in_sizes, int n_in,
                              void* d_out, int out_size, void* d_ws, size_t ws_size,
                              hipStream_t stream) {
    const float* hs  = (const float*)d_in[0];
    const int*   am  = (const int*)d_in[1];
    const float* wq  = (const float*)d_in[2];
    const float* wk  = (const float*)d_in[3];
    const float* wv_ = (const float*)d_in[4];
    const float* wo  = (const float*)d_in[5];
    const float* bo  = (const float*)d_in[6];
    float* out = (float*)d_out;

    char* ws = (char*)d_ws;
    unsigned short* Xb  = (unsigned short*)ws;                               // 16 MiB: X bf16; later VT
    unsigned short* Wt  = (unsigned short*)(ws + (size_t)16 * 1024 * 1024);  // 32 MiB: 4x Wt bf16
    unsigned short* QKV = (unsigned short*)(ws + (size_t)48 * 1024 * 1024);  // 48 MiB: Q,K,V bf16
    unsigned short* CTX = (unsigned short*)(ws + (size_t)96 * 1024 * 1024);  // 16 MiB: ctx bf16
    unsigned short* VT  = Xb;                                                // alias (Xb dead after projections)

    const int LDSB_8PH = 131072;      // 128 KiB dynamic LDS
    const int LDSB_R   = 147456;      // 144 KiB dynamic LDS
    static bool attrSet = false;
    if (!attrSet) {
        hipFuncSetAttribute((const void*)gemm8ph_kernel, hipFuncAttributeMaxDynamicSharedMemorySize, LDSB_8PH);
        hipFuncSetAttribute((const void*)gemm8_kernel<0>, hipFuncAttributeMaxDynamicSharedMemorySize, LDSB_R);
        hipFuncSetAttribute((const void*)gemm8_kernel<1>, hipFuncAttributeMaxDynamicSharedMemorySize, LDSB_R);
        attrSet = true;
    }

    hipLaunchKernelGGL(cvt_x_kernel, dim3(Mv * Dv / 8 / 256), dim3(256), 0, stream, hs, Xb);
    hipLaunchKernelGGL(cvt_wt_kernel, dim3(32, 32, 4), dim3(256), 0, stream, wq, wk, wv_, wo, Wt);
    // QK projection: 8-phase 256^2, N=4096 (wq,wk), 256 blocks = 1 exact CU round
    hipLaunchKernelGGL(gemm8ph_kernel, dim3(256), dim3(512), LDSB_8PH, stream, Xb, Wt, QKV);
    // V projection: ring gemm, N=2048 (wv), 256 blocks = 1 exact CU round, bf16 out
    hipLaunchKernelGGL(gemm8_kernel<0>, dim3(256), dim3(512), LDSB_R, stream,
                       Xb, Wt + 2 * (size_t)Dv * Dv, QKV + 2 * (size_t)Mv * Dv, (float*)nullptr, (const float*)nullptr);
    hipLaunchKernelGGL(vt_kernel, dim3(32, 32, 2), dim3(256), 0, stream,
                       QKV + 2 * (size_t)Mv * Dv, VT);
    // attention: R9 structure, 512 blocks x 512 thr (16 waves/CU)
    hipLaunchKernelGGL(attn_kernel, dim3(512), dim3(512), 0, stream,
                       QKV, QKV + (size_t)Mv * Dv, VT, am, CTX);
    // out-proj: N=2048, 256 blocks = 1 exact CU round, fp32 + bias
    hipLaunchKernelGGL(gemm8_kernel<1>, dim3(256), dim3(512), LDSB_R, stream,
                       CTX, Wt + 3 * (size_t)Dv * Dv, (unsigned short*)nullptr, out, bo);
}

// Round 14
// 227.485 us; speedup vs baseline: 1.2357x; 1.0401x over previous
//
#include <hip/hip_runtime.h>
#include <hip/hip_bf16.h>
#include <stdint.h>

// Problem constants (FlaxGPTNeoSelfAttention): B=2, S=2048, D=2048, H=16, HD=128
#define Bv 2
#define Sv 2048
#define Dv 2048
#define Hv 16
#define HDv 128
#define Mv (Bv*Sv)   // 4096 rows for the projection GEMMs

typedef __attribute__((ext_vector_type(8))) short short8;
typedef __attribute__((ext_vector_type(4))) short short4v;
typedef __attribute__((ext_vector_type(4))) float f32x4;

__device__ __forceinline__ unsigned short bf16_rne(float f) {
    union { float f; uint32_t u; } c; c.f = f;
    uint32_t u = c.u;
    u += 0x7fffu + ((u >> 16) & 1u);   // round-to-nearest-even
    return (unsigned short)(u >> 16);
}

__device__ __forceinline__ uint32_t cvt_pk_bf16(float lo, float hi) {
    uint32_t r;
    asm("v_cvt_pk_bf16_f32 %0, %1, %2" : "=v"(r) : "v"(lo), "v"(hi));
    return r;
}

__device__ __forceinline__ void gload16(const void* g, void* l) {
    // async global->LDS, 16B per lane; LDS dest = wave-uniform base + lane*16
    __builtin_amdgcn_global_load_lds((const __attribute__((address_space(1))) void*)g,
                                     (__attribute__((address_space(3))) void*)l, 16, 0, 0);
}

#define BARRIER() asm volatile("s_barrier" ::: "memory")
#define LGKM0()   do { asm volatile("s_waitcnt lgkmcnt(0)" ::: "memory"); \
                       __builtin_amdgcn_sched_barrier(0); } while (0)

// ---------------- kernel 1: hidden_states fp32 -> bf16 (16B loads, 16B stores) ----------------
__global__ void cvt_x_kernel(const float* __restrict__ x, unsigned short* __restrict__ xb) {
    int i = (blockIdx.x * 256 + threadIdx.x) * 8;
    float4 v0 = *(const float4*)(x + i);
    float4 v1 = *(const float4*)(x + i + 4);
    short8 o;
    o[0] = (short)bf16_rne(v0.x); o[1] = (short)bf16_rne(v0.y);
    o[2] = (short)bf16_rne(v0.z); o[3] = (short)bf16_rne(v0.w);
    o[4] = (short)bf16_rne(v1.x); o[5] = (short)bf16_rne(v1.y);
    o[6] = (short)bf16_rne(v1.z); o[7] = (short)bf16_rne(v1.w);
    *(short8*)(xb + i) = o;
}

// ---------------- kernel 2: weights fp32 -> bf16, transposed Wt[n][k] (vectorized) ----------------
__global__ void cvt_wt_kernel(const float* __restrict__ w0, const float* __restrict__ w1,
                              const float* __restrict__ w2, const float* __restrict__ w3,
                              unsigned short* __restrict__ wt) {
    __shared__ unsigned short t[64 * 65];   // t[kk][nn], padded
    const int tid = threadIdx.x;
    int z = blockIdx.z;
    const float* w = (z == 0) ? w0 : (z == 1) ? w1 : (z == 2) ? w2 : w3;
    unsigned short* o = wt + (size_t)z * Dv * Dv;
    int k0 = blockIdx.x * 64, n0 = blockIdx.y * 64;
    #pragma unroll
    for (int j = 0; j < 4; ++j) {
        int r = (tid >> 4) + j * 16;         // kk
        int c = (tid & 15) * 4;              // nn
        float4 v = *(const float4*)&w[(size_t)(k0 + r) * Dv + n0 + c];
        t[r * 65 + c + 0] = bf16_rne(v.x);
        t[r * 65 + c + 1] = bf16_rne(v.y);
        t[r * 65 + c + 2] = bf16_rne(v.z);
        t[r * 65 + c + 3] = bf16_rne(v.w);
    }
    __syncthreads();
    #pragma unroll
    for (int j = 0; j < 2; ++j) {
        int flat = tid + j * 256;
        int nn = flat >> 3;                  // 0..63
        int kk = (flat & 7) * 8;
        short8 v;
        #pragma unroll
        for (int e = 0; e < 8; ++e) v[e] = (short)t[(kk + e) * 65 + nn];
        *(short8*)&o[(size_t)(n0 + nn) * Dv + k0 + kk] = v;
    }
}

// ---------------- kernel 3a: QK projection, 8-phase 256x256 (R6 kernel, balanced 256-block grid) ----------------
__global__ __launch_bounds__(512, 2) void gemm8ph_kernel(
    const unsigned short* __restrict__ A,
    const unsigned short* __restrict__ WtBase,
    unsigned short* __restrict__ CbBase)
{
    extern __shared__ unsigned short lds[];   // 65536 shorts = 128 KiB
    const int tid = threadIdx.x;
    const int wv = tid >> 6, ln = tid & 63;
    const int lr = ln & 15, lg = ln >> 4;
    const int wm = wv >> 2, wn = wv & 3;      // 2 x 4 waves

    const int bid = blockIdx.x;
    const int xcd = bid & 7, idx = bid >> 3;
    const int n_idx = xcd * 2 + idx / 16;     // 0..15
    const int m_idx = idx % 16;
    const int m0 = m_idx * 256, n0g = n_idx * 256;

    const int lrow = wv * 8 + (ln >> 3);
    const int lcol = ((ln & 7) ^ (ln >> 3)) << 3;
    const unsigned short* Ag = A      + (size_t)(m0  + lrow) * Dv + lcol;
    const unsigned short* Bg = WtBase + (size_t)(n0g + lrow) * Dv + lcol;

    auto SH = [&](int T, int isB, int h) {
        const unsigned short* src = (isB ? Bg : Ag) + (size_t)(h * 128) * Dv + T * 64;
        unsigned short* dst = &lds[(T & 1) * 32768 + isB * 16384 + h * 8192 + wv * 512];
        gload16(src, dst);
        gload16(src + (size_t)64 * Dv, dst + 4096);
    };

    const int axk = lr & 7;
    auto RDA = [&](int buf, int fm, int ks) {
        return *(const short8*)&lds[buf * 32768 + (wm * 128 + fm * 16 + lr) * 64 + (((ks * 4 + lg) ^ axk) << 3)];
    };
    auto RDB = [&](int buf, int fn, int ks) {
        return *(const short8*)&lds[buf * 32768 + 16384 + (wn * 64 + fn * 16 + lr) * 64 + (((ks * 4 + lg) ^ axk) << 3)];
    };

    f32x4 acc[8][4];
    #pragma unroll
    for (int fm = 0; fm < 8; fm++)
        #pragma unroll
        for (int fn = 0; fn < 4; fn++)
            acc[fm][fn] = (f32x4){0.f, 0.f, 0.f, 0.f};

    // prologue: T0 full (4 halves), then T1.B0, T1.A0 (matches steady-state lag)
    SH(0, 0, 0); SH(0, 0, 1); SH(0, 1, 0); SH(0, 1, 1);
    SH(1, 1, 0); SH(1, 0, 0);
    asm volatile("s_waitcnt vmcnt(4)" ::: "memory");
    BARRIER();

    short8 af[8], b0[4], b1[4];
    const int NT2 = 16;                        // 32 K-tiles, 2 per iteration

    #define MFMA_BLK(FN0, FN1, BARR) do {                                              \
        __builtin_amdgcn_s_setprio(1);                                                 \
        _Pragma("unroll")                                                              \
        for (int fm = 0; fm < 8; fm++) {                                               \
            acc[fm][FN0] = __builtin_amdgcn_mfma_f32_16x16x32_bf16(af[fm], BARR[FN0], acc[fm][FN0], 0, 0, 0); \
            acc[fm][FN1] = __builtin_amdgcn_mfma_f32_16x16x32_bf16(af[fm], BARR[FN1], acc[fm][FN1], 0, 0, 0); \
        }                                                                              \
        __builtin_amdgcn_s_setprio(0);                                                 \
    } while (0)

    for (int i = 0; i < NT2; ++i) {
        const int Tb = 2 * i + 1;
        const bool more = (i + 1 < NT2);

        // ======== group A: tile 2i in buf0 ========
        #pragma unroll
        for (int fm = 0; fm < 8; fm++) af[fm] = RDA(0, fm, 0);
        #pragma unroll
        for (int fn = 0; fn < 4; fn++) b0[fn] = RDB(0, fn, 0);
        SH(Tb, 0, 1);
        BARRIER(); LGKM0();
        MFMA_BLK(0, 1, b0);
        BARRIER();

        #pragma unroll
        for (int fn = 0; fn < 4; fn++) b1[fn] = RDB(0, fn, 1);
        SH(Tb, 1, 1);
        BARRIER(); LGKM0();
        MFMA_BLK(2, 3, b0);
        BARRIER();

        #pragma unroll
        for (int fm = 0; fm < 8; fm++) af[fm] = RDA(0, fm, 1);
        if (more) SH(Tb + 1, 1, 0);
        BARRIER(); LGKM0();
        MFMA_BLK(0, 1, b1);
        BARRIER();

        if (more) SH(Tb + 1, 0, 0);
        BARRIER(); LGKM0();
        MFMA_BLK(2, 3, b1);
        if (more) asm volatile("s_waitcnt vmcnt(4)" ::: "memory");
        else      asm volatile("s_waitcnt vmcnt(0)" ::: "memory");
        BARRIER();

        // ======== group B: tile 2i+1 in buf1 ========
        #pragma unroll
        for (int fm = 0; fm < 8; fm++) af[fm] = RDA(1, fm, 0);
        #pragma unroll
        for (int fn = 0; fn < 4; fn++) b0[fn] = RDB(1, fn, 0);
        if (more) SH(Tb + 1, 0, 1);
        BARRIER(); LGKM0();
        MFMA_BLK(0, 1, b0);
        BARRIER();

        #pragma unroll
        for (int fn = 0; fn < 4; fn++) b1[fn] = RDB(1, fn, 1);
        if (more) SH(Tb + 1, 1, 1);
        BARRIER(); LGKM0();
        MFMA_BLK(2, 3, b0);
        BARRIER();

        #pragma unroll
        for (int fm = 0; fm < 8; fm++) af[fm] = RDA(1, fm, 1);
        if (more) SH(Tb + 2, 1, 0);
        BARRIER(); LGKM0();
        MFMA_BLK(0, 1, b1);
        BARRIER();

        if (more) SH(Tb + 2, 0, 0);
        BARRIER(); LGKM0();
        MFMA_BLK(2, 3, b1);
        if (more) {
            asm volatile("s_waitcnt vmcnt(4)" ::: "memory");
            BARRIER();
        }
    }
    #undef MFMA_BLK

    // epilogue: bf16 stores, z = n-panel / 8 (Q at z=0, K at z=1)
    const int z = n0g >> 11;
    unsigned short* Cz = CbBase + (size_t)z * Mv * Dv;
    const int ncl = (n0g & 2047) + wn * 64;
    #pragma unroll
    for (int fm = 0; fm < 8; fm++)
        #pragma unroll
        for (int fn = 0; fn < 4; fn++) {
            int row = m0 + wm * 128 + fm * 16 + lg * 4;
            int col = ncl + fn * 16 + lr;
            #pragma unroll
            for (int r = 0; r < 4; r++)
                Cz[(size_t)(row + r) * Dv + col] = bf16_rne(acc[fm][fn][r]);
        }
}

// ---------------- kernel 3b/5: ring GEMM (R4 proven structure), 128x256 tile, N=2048, 256 blocks ----------------
// FOUT=0: V projection -> fused TRANSPOSED store VT[b][c][s] via LDS (Cb = VT base).
// FOUT=1: fp32 store with +bias (out-proj).
template<int FOUT>
__global__ __launch_bounds__(512, 2) void gemm8_kernel(
    const unsigned short* __restrict__ A,
    const unsigned short* __restrict__ WtBase,
    unsigned short* __restrict__ Cb,
    float* __restrict__ Cf,
    const float* __restrict__ bias)
{
    extern __shared__ unsigned short lds[];    // 3 bufs x (A 8192 + B 16384) shorts = 144 KiB
    const int tid = threadIdx.x;
    const int wv = tid >> 6, ln = tid & 63;
    const int lr = ln & 15, lg = ln >> 4;
    const int wm = wv >> 2, wn = wv & 3;

    const int bid = blockIdx.x;
    const int xcd = bid & 7, idx = bid >> 3;
    const int n_idx = xcd;                     // 8 n-panels, 1 per XCD
    const int m_idx = idx;                     // 32 m-panels
    const int m0 = m_idx * 128;
    const int n0g = n_idx * 256;
    const int NT = Dv / 64;

    const int srow = ln >> 3;
    const int swz = ((ln & 7) ^ srow) << 3;
    const unsigned short* Ab = A      + (size_t)(m0  + wv * 8 + srow) * Dv + swz;
    const unsigned short* Bb = WtBase + (size_t)(n0g + wv * 8 + srow) * Dv + swz;

    auto STAGE_A = [&](int t, int d) {
        const unsigned short* g = Ab + t * 64;
        #pragma unroll
        for (int j = 0; j < 2; ++j)
            gload16(g + (size_t)(j * 64) * Dv, &lds[d * 24576 + (j * 64 + wv * 8) * 64]);
    };
    auto STAGE_B = [&](int t, int d) {
        const unsigned short* g = Bb + t * 64;
        #pragma unroll
        for (int j = 0; j < 4; ++j)
            gload16(g + (size_t)(j * 64) * Dv, &lds[d * 24576 + 8192 + (j * 64 + wv * 8) * 64]);
    };

    const int aro = (wm * 64 + lr) * 64;
    const int bro = (wn * 64 + lr) * 64;
    const int ach0 = ((lg ^ (lr & 7)) << 3);
    const int ach1 = (((4 + lg) ^ (lr & 7)) << 3);

    f32x4 acc[4][4];
    #pragma unroll
    for (int mi = 0; mi < 4; mi++)
        #pragma unroll
        for (int ni = 0; ni < 4; ni++)
            acc[mi][ni] = (f32x4){0.f, 0.f, 0.f, 0.f};

    STAGE_A(0, 0); STAGE_B(0, 0);
    STAGE_A(1, 1); STAGE_B(1, 1);
    asm volatile("s_waitcnt vmcnt(6)" ::: "memory");
    BARRIER();

    for (int t = 0; t < NT; ++t) {
        const int d = t % 3, d2 = (t + 2) % 3;
        const unsigned short* la = &lds[d * 24576];
        const unsigned short* lb = &lds[d * 24576 + 8192];

        short8 af[4][2], bf0[2][2];
        #pragma unroll
        for (int mi = 0; mi < 4; mi++) {
            af[mi][0] = *(const short8*)&la[aro + mi * 1024 + ach0];
            af[mi][1] = *(const short8*)&la[aro + mi * 1024 + ach1];
        }
        #pragma unroll
        for (int ni = 0; ni < 2; ni++) {
            bf0[ni][0] = *(const short8*)&lb[bro + ni * 1024 + ach0];
            bf0[ni][1] = *(const short8*)&lb[bro + ni * 1024 + ach1];
        }
        if (t + 2 < NT) STAGE_A(t + 2, d2);
        BARRIER();
        __builtin_amdgcn_s_setprio(1);
        #pragma unroll
        for (int mi = 0; mi < 4; mi++)
            #pragma unroll
            for (int ni = 0; ni < 2; ni++) {
                acc[mi][ni] = __builtin_amdgcn_mfma_f32_16x16x32_bf16(af[mi][0], bf0[ni][0], acc[mi][ni], 0, 0, 0);
                acc[mi][ni] = __builtin_amdgcn_mfma_f32_16x16x32_bf16(af[mi][1], bf0[ni][1], acc[mi][ni], 0, 0, 0);
            }
        __builtin_amdgcn_s_setprio(0);

        short8 bf1[2][2];
        #pragma unroll
        for (int ni = 0; ni < 2; ni++) {
            bf1[ni][0] = *(const short8*)&lb[bro + (ni + 2) * 1024 + ach0];
            bf1[ni][1] = *(const short8*)&lb[bro + (ni + 2) * 1024 + ach1];
        }
        if (t + 2 < NT) STAGE_B(t + 2, d2);
        asm volatile("s_waitcnt vmcnt(6)" ::: "memory");
        BARRIER();
        __builtin_amdgcn_s_setprio(1);
        #pragma unroll
        for (int mi = 0; mi < 4; mi++)
            #pragma unroll
            for (int ni = 0; ni < 2; ni++) {
                acc[mi][ni + 2] = __builtin_amdgcn_mfma_f32_16x16x32_bf16(af[mi][0], bf1[ni][0], acc[mi][ni + 2], 0, 0, 0);
                acc[mi][ni + 2] = __builtin_amdgcn_mfma_f32_16x16x32_bf16(af[mi][1], bf1[ni][1], acc[mi][ni + 2], 0, 0, 0);
            }
        __builtin_amdgcn_s_setprio(0);
    }

    if (FOUT) {
        #pragma unroll
        for (int mi = 0; mi < 4; mi++)
            #pragma unroll
            for (int ni = 0; ni < 4; ni++) {
                int row = m0 + wm * 64 + mi * 16 + lg * 4;
                int col = n0g + wn * 64 + ni * 16 + lr;
                float bv = bias[col];
                #pragma unroll
                for (int r = 0; r < 4; r++)
                    Cf[(size_t)(row + r) * Dv + col] = acc[mi][ni][r] + bv;
            }
    } else {
        // fused V transpose: acc -> LDS T[col][s] (chunk-XOR swizzled) -> coalesced VT store
        __syncthreads();                      // all ring reads complete
        unsigned short* T = lds;              // 256 cols x 128 s x bf16 = 64 KiB
        #pragma unroll
        for (int mi = 0; mi < 4; mi++)
            #pragma unroll
            for (int ni = 0; ni < 4; ni++) {
                int row = wm * 64 + mi * 16 + lg * 4;     // local s (mult of 4)
                int col = wn * 64 + ni * 16 + lr;         // local c
                int cb = (row >> 2) ^ (col & 31);
                short4v o;
                #pragma unroll
                for (int r = 0; r < 4; r++) o[r] = (short)bf16_rne(acc[mi][ni][r]);
                *(short4v*)&T[col * 128 + cb * 4] = o;
            }
        __syncthreads();
        const int bb = m0 >> 11;
        const int s0 = m0 & 2047;
        unsigned short* VTb = Cb + (size_t)bb * Dv * Sv;
        #pragma unroll
        for (int j = 0; j < 8; ++j) {
            int flat = tid + j * 512;          // 0..4095
            int col = flat >> 4;               // 0..255
            int s16 = flat & 15;               // 16B chunk along s (8 shorts)
            int c5 = col & 31;
            short4v lo = *(const short4v*)&T[col * 128 + (((s16 * 2)     ^ c5) << 2)];
            short4v hi = *(const short4v*)&T[col * 128 + (((s16 * 2 + 1) ^ c5) << 2)];
            short8 v;
            v[0] = lo[0]; v[1] = lo[1]; v[2] = lo[2]; v[3] = lo[3];
            v[4] = hi[0]; v[5] = hi[1]; v[6] = hi[2]; v[7] = hi[3];
            *(short8*)&VTb[(size_t)(n0g + col) * Sv + s0 + s16 * 8] = v;
        }
    }
}

// ---------------- kernel 4: causal flash attention (R9 proven: 512 blocks, 8 waves, 16q/wave) ----------------
__global__ __launch_bounds__(512) void attn_kernel(
    const unsigned short* __restrict__ Q, const unsigned short* __restrict__ K,
    const unsigned short* __restrict__ VT, const int* __restrict__ pmask,
    unsigned short* __restrict__ CTX)
{
    __shared__ unsigned short lK[2][64 * 128];
    __shared__ unsigned short lVt[2][128 * 64];
    __shared__ int lPmB[2][64];
    __shared__ int lPmOk[2];

    const int tid = threadIdx.x, wv = tid >> 6, ln = tid & 63;
    const int lr = ln & 15, lg = ln >> 4;
    const int L = blockIdx.x;
    const int bh = (L & 7) * 4 + ((L >> 3) & 3);
    const int b = bh >> 4, h = bh & 15;
    const int v = L >> 5;
    const int qidx = (v < 8) ? (15 - v) : (v - 8);
    const int q0 = qidx * 128;
    const int qw0 = q0 + wv * 16;
    const size_t hoff  = (size_t)b * Sv * Dv + (size_t)h * HDv;
    const size_t vtoff = ((size_t)b * Dv + (size_t)h * HDv) * Sv;

    short8 qf[4];
    #pragma unroll
    for (int ds = 0; ds < 4; ds++)
        qf[ds] = *(const short8*)&Q[hoff + (size_t)(qw0 + lr) * Dv + ds * 32 + lg * 8];

    size_t koff[2], voff[2];
    #pragma unroll
    for (int ii = 0; ii < 2; ++ii) {
        int slot = ii * 512 + wv * 64 + ln;
        int krow = slot >> 4, kch = slot & 15;
        koff[ii] = hoff + (size_t)krow * Dv + ((kch ^ (krow & 7)) << 3);
        int vrow = slot >> 3, vch = slot & 7;
        voff[ii] = vtoff + (size_t)vrow * Sv + ((vch ^ (vrow & 7)) << 3);
    }

    auto STAGE = [&](int t, int buf) {
        const size_t kadd = (size_t)(t << 6) * Dv;
        const int vadd = t << 6;
        unsigned short* kb = &lK[buf][0];
        unsigned short* vb = &lVt[buf][0];
        #pragma unroll
        for (int ii = 0; ii < 2; ++ii) {
            gload16(K + koff[ii] + kadd, kb + (ii * 512 + wv * 64) * 8);
            gload16(VT + voff[ii] + vadd, vb + (ii * 512 + wv * 64) * 8);
        }
        if (wv == 0) {
            int pmv = pmask[b * Sv + (t << 6) + ln];
            lPmB[buf][ln] = pmv;
            unsigned long long bal = __ballot(pmv != 0);
            if (ln == 0) lPmOk[buf] = (bal == ~0ull) ? 1 : 0;
        }
    };

    f32x4 acc[8];
    #pragma unroll
    for (int n = 0; n < 8; n++) acc[n] = (f32x4){0.f, 0.f, 0.f, 0.f};
    float mrow = -3.0e38f, lrow = 0.f;
    const float CS = 0.12751744f;
    const int qg = qw0 + lr;
    const int nt = (q0 >> 6) + 2;
    const int srcA = lr + ((lg & 1) << 5);
    const int srcB = srcA + 16;
    const bool hiSel = (lg >= 2);

    auto TILE = [&](int t, int buf, auto CAUSAL_c) {
        constexpr bool CAUSAL = decltype(CAUSAL_c)::value;
        const int kv0 = t << 6;
        const unsigned short* kb = &lK[buf][0];
        const unsigned short* vb = &lVt[buf][0];

        f32x4 st[4];
        #pragma unroll
        for (int t2 = 0; t2 < 4; ++t2) st[t2] = (f32x4){0.f, 0.f, 0.f, 0.f};
        __builtin_amdgcn_s_setprio(1);
        #pragma unroll
        for (int t2 = 0; t2 < 4; ++t2) {
            const int krow = t2 * 16 + lr;
            #pragma unroll
            for (int ds = 0; ds < 4; ++ds) {
                const int ch = ds * 4 + lg;
                short8 kf = *(const short8*)&kb[krow * 128 + ((ch ^ (krow & 7)) << 3)];
                st[t2] = __builtin_amdgcn_mfma_f32_16x16x32_bf16(kf, qf[ds], st[t2], 0, 0, 0);
            }
        }
        __builtin_amdgcn_s_setprio(0);

        float sv[4][4];
        float rmax;
        if constexpr (CAUSAL) {
            const int* pm = &lPmB[buf][0];
            #pragma unroll
            for (int t2 = 0; t2 < 4; ++t2)
                #pragma unroll
                for (int r = 0; r < 4; ++r) {
                    int kvl = t2 * 16 + lg * 4 + r;
                    bool ok = ((kv0 + kvl) <= qg) && (pm[kvl] != 0);
                    sv[t2][r] = ok ? st[t2][r] * CS : -1.0e30f;
                }
            rmax = sv[0][0];
            #pragma unroll
            for (int t2 = 0; t2 < 4; ++t2)
                #pragma unroll
                for (int r = 0; r < 4; ++r) rmax = fmaxf(rmax, sv[t2][r]);
            rmax = fmaxf(rmax, __shfl_xor(rmax, 16, 64));
            rmax = fmaxf(rmax, __shfl_xor(rmax, 32, 64));
        } else {
            rmax = st[0][0];
            #pragma unroll
            for (int t2 = 0; t2 < 4; ++t2)
                #pragma unroll
                for (int r = 0; r < 4; ++r) rmax = fmaxf(rmax, st[t2][r]);
            rmax = fmaxf(rmax, __shfl_xor(rmax, 16, 64));
            rmax = fmaxf(rmax, __shfl_xor(rmax, 32, 64));
            rmax *= CS;
        }

        if (!__all(rmax - mrow <= 8.0f)) {
            float mn = fmaxf(mrow, rmax);
            float alpha = exp2f(mrow - mn);
            mrow = mn;
            lrow *= alpha;
            #pragma unroll
            for (int n = 0; n < 8; n++)
                #pragma unroll
                for (int r = 0; r < 4; r++) acc[n][r] *= alpha;
        }

        float p[4][4]; float psum = 0.f;
        if constexpr (CAUSAL) {
            #pragma unroll
            for (int t2 = 0; t2 < 4; ++t2)
                #pragma unroll
                for (int r = 0; r < 4; ++r) {
                    float e = exp2f(sv[t2][r] - mrow);
                    p[t2][r] = (sv[t2][r] > -5.0e29f) ? e : 0.f;
                    psum += p[t2][r];
                }
        } else {
            if (lPmOk[buf]) {
                #pragma unroll
                for (int t2 = 0; t2 < 4; ++t2)
                    #pragma unroll
                    for (int r = 0; r < 4; ++r) {
                        p[t2][r] = exp2f(fmaf(st[t2][r], CS, -mrow));
                        psum += p[t2][r];
                    }
            } else {
                const int* pm = &lPmB[buf][0];
                #pragma unroll
                for (int t2 = 0; t2 < 4; ++t2)
                    #pragma unroll
                    for (int r = 0; r < 4; ++r) {
                        int kvl = t2 * 16 + lg * 4 + r;
                        float e = exp2f(fmaf(st[t2][r], CS, -mrow));
                        p[t2][r] = (pm[kvl] != 0) ? e : 0.f;
                        psum += p[t2][r];
                    }
            }
        }
        psum += __shfl_xor(psum, 16, 64);
        psum += __shfl_xor(psum, 32, 64);
        lrow += psum;

        uint32_t pk[4][2];
        #pragma unroll
        for (int t2 = 0; t2 < 4; ++t2)
            #pragma unroll
            for (int pp = 0; pp < 2; ++pp)
                pk[t2][pp] = cvt_pk_bf16(p[t2][2 * pp], p[t2][2 * pp + 1]);

        union U { uint32_t u[4]; short8 s; } pa0, pa1;
        {
            uint32_t l0 = (uint32_t)__shfl((int)pk[0][0], srcA, 64), h0 = (uint32_t)__shfl((int)pk[1][0], srcA, 64);
            uint32_t l1 = (uint32_t)__shfl((int)pk[0][1], srcA, 64), h1 = (uint32_t)__shfl((int)pk[1][1], srcA, 64);
            uint32_t l2 = (uint32_t)__shfl((int)pk[0][0], srcB, 64), h2 = (uint32_t)__shfl((int)pk[1][0], srcB, 64);
            uint32_t l3 = (uint32_t)__shfl((int)pk[0][1], srcB, 64), h3 = (uint32_t)__shfl((int)pk[1][1], srcB, 64);
            pa0.u[0] = hiSel ? h0 : l0; pa0.u[1] = hiSel ? h1 : l1;
            pa0.u[2] = hiSel ? h2 : l2; pa0.u[3] = hiSel ? h3 : l3;
        }
        {
            uint32_t l0 = (uint32_t)__shfl((int)pk[2][0], srcA, 64), h0 = (uint32_t)__shfl((int)pk[3][0], srcA, 64);
            uint32_t l1 = (uint32_t)__shfl((int)pk[2][1], srcA, 64), h1 = (uint32_t)__shfl((int)pk[3][1], srcA, 64);
            uint32_t l2 = (uint32_t)__shfl((int)pk[2][0], srcB, 64), h2 = (uint32_t)__shfl((int)pk[3][0], srcB, 64);
            uint32_t l3 = (uint32_t)__shfl((int)pk[2][1], srcB, 64), h3 = (uint32_t)__shfl((int)pk[3][1], srcB, 64);
            pa1.u[0] = hiSel ? h0 : l0; pa1.u[1] = hiSel ? h1 : l1;
            pa1.u[2] = hiSel ? h2 : l2; pa1.u[3] = hiSel ? h3 : l3;
        }

        __builtin_amdgcn_s_setprio(1);
        #pragma unroll
        for (int n = 0; n < 8; n++) {
            const int vrow = n * 16 + lr;
            short8 a0 = *(const short8*)&vb[vrow * 64 + ((lg ^ (vrow & 7)) << 3)];
            acc[n] = __builtin_amdgcn_mfma_f32_16x16x32_bf16(a0, pa0.s, acc[n], 0, 0, 0);
            short8 a1 = *(const short8*)&vb[vrow * 64 + (((4 + lg) ^ (vrow & 7)) << 3)];
            acc[n] = __builtin_amdgcn_mfma_f32_16x16x32_bf16(a1, pa1.s, acc[n], 0, 0, 0);
        }
        __builtin_amdgcn_s_setprio(0);
    };

    STAGE(0, 0);
    __syncthreads();
    int cur = 0;

    for (int t = 0; t < nt; ++t) {
        if (t + 1 < nt) STAGE(t + 1, cur ^ 1);
        const int kv0 = t << 6;
        if (kv0 <= qw0 + 15) {
            if (kv0 + 63 > qw0) TILE(t, cur, std::integral_constant<bool, true>{});
            else                TILE(t, cur, std::integral_constant<bool, false>{});
        }
        __syncthreads();
        cur ^= 1;
    }

    float inv = 1.0f / lrow;
    #pragma unroll
    for (int n = 0; n < 8; n++) {
        short4v o;
        #pragma unroll
        for (int r = 0; r < 4; r++) o[r] = (short)bf16_rne(acc[n][r] * inv);
        *(short4v*)&CTX[hoff + (size_t)qg * Dv + n * 16 + lg * 4] = o;
    }
}

// ---------------- launcher ----------------
extern "C" void kernel_launch(void* const* d_in, const int* in_sizes, int n_in,
                              void* d_out, int out_size, void* d_ws, size_t ws_size,
                              hipStream_t stream) {
    const float* hs  = (const float*)d_in[0];
    const int*   am  = (const int*)d_in[1];
    const float* wq  = (const float*)d_in[2];
    const float* wk  = (const float*)d_in[3];
    const float* wv_ = (const float*)d_in[4];
    const float* wo  = (const float*)d_in[5];
    const float* bo  = (const float*)d_in[6];
    float* out = (float*)d_out;

    char* ws = (char*)d_ws;
    unsigned short* Xb  = (unsigned short*)ws;                               // 16 MiB: X bf16
    unsigned short* Wt  = (unsigned short*)(ws + (size_t)16 * 1024 * 1024);  // 32 MiB: 4x Wt bf16
    unsigned short* QKV = (unsigned short*)(ws + (size_t)48 * 1024 * 1024);  // 48 MiB: Q,K,VT bf16
    unsigned short* CTX = (unsigned short*)(ws + (size_t)96 * 1024 * 1024);  // 16 MiB: ctx bf16
    unsigned short* VT  = QKV + 2 * (size_t)Mv * Dv;                         // V stored transposed (fused)

    const int LDSB_8PH = 131072;      // 128 KiB dynamic LDS
    const int LDSB_R   = 147456;      // 144 KiB dynamic LDS
    static bool attrSet = false;
    if (!attrSet) {
        hipFuncSetAttribute((const void*)gemm8ph_kernel, hipFuncAttributeMaxDynamicSharedMemorySize, LDSB_8PH);
        hipFuncSetAttribute((const void*)gemm8_kernel<0>, hipFuncAttributeMaxDynamicSharedMemorySize, LDSB_R);
        hipFuncSetAttribute((const void*)gemm8_kernel<1>, hipFuncAttributeMaxDynamicSharedMemorySize, LDSB_R);
        attrSet = true;
    }

    hipLaunchKernelGGL(cvt_x_kernel, dim3(Mv * Dv / 8 / 256), dim3(256), 0, stream, hs, Xb);
    hipLaunchKernelGGL(cvt_wt_kernel, dim3(32, 32, 4), dim3(256), 0, stream, wq, wk, wv_, wo, Wt);
    // QK projection: 8-phase 256^2, N=4096 (wq,wk), 256 blocks = 1 exact CU round
    hipLaunchKernelGGL(gemm8ph_kernel, dim3(256), dim3(512), LDSB_8PH, stream, Xb, Wt, QKV);
    // V projection with FUSED transpose: writes VT[b][c][s] directly (vt_kernel eliminated)
    hipLaunchKernelGGL(gemm8_kernel<0>, dim3(256), dim3(512), LDSB_R, stream,
                       Xb, Wt + 2 * (size_t)Dv * Dv, VT, (float*)nullptr, (const float*)nullptr);
    // attention: R9 structure, 512 blocks x 512 thr (16 waves/CU)
    hipLaunchKernelGGL(attn_kernel, dim3(512), dim3(512), 0, stream,
                       QKV, QKV + (size_t)Mv * Dv, VT, am, CTX);
    // out-proj: N=2048, 256 blocks = 1 exact CU round, fp32 + bias
    hipLaunchKernelGGL(gemm8_kernel<1>, dim3(256), dim3(512), LDSB_R, stream,
                       CTX, Wt + 3 * (size_t)Dv * Dv, (unsigned short*)nullptr, out, bo);
}